// Round 1
// baseline (5863.847 us; speedup 1.0000x reference)
//
#include <hip/hip_runtime.h>

#define Bz   64
#define Tz   512
#define DIN  256
#define DOUT 1024
#define MODSZ 128

// ---------------------------------------------------------------------------
// Pass 1: Z = x @ W_in + b_in  -> written into d_out's ys region (same layout:
// row n = b*T + t, so Z[n, c] lives exactly where ys[b, t, c] will go).
// Tile 128 rows x 64 cols, K-chunks of 32, 256 threads, 8x4 accum per thread
// (rows split as [4tr..4tr+3] and [64+4tr..64+4tr+3] to keep LDS reads 2-way).
// ---------------------------------------------------------------------------
__global__ __launch_bounds__(256) void zgemm_kernel(
    const float* __restrict__ x, const float* __restrict__ Win,
    const float* __restrict__ bin, float* __restrict__ out)
{
    __shared__ float xT[32 * 132];   // [kk][r], stride 132 (16B-aligned rows, pads banks)
    __shared__ float ws[32 * 68];    // [kk][c], stride 68

    const int n0 = blockIdx.x * 128;
    const int c0 = blockIdx.y * 64;
    const int tid = threadIdx.x;
    const int tr = tid >> 4;   // 0..15
    const int tc = tid & 15;   // 0..15

    float acc[8][4];
#pragma unroll
    for (int i = 0; i < 8; ++i)
#pragma unroll
        for (int j = 0; j < 4; ++j) acc[i][j] = 0.f;

    for (int k0 = 0; k0 < DIN; k0 += 32) {
        // x tile 128x32 -> transposed into xT[kk][r]
#pragma unroll
        for (int p = 0; p < 4; ++p) {
            int s = tid + p * 256;           // 0..1023
            int r = s >> 3, kq = s & 7;
            float4 v = *(const float4*)(x + (size_t)(n0 + r) * DIN + k0 + kq * 4);
            xT[(kq * 4 + 0) * 132 + r] = v.x;
            xT[(kq * 4 + 1) * 132 + r] = v.y;
            xT[(kq * 4 + 2) * 132 + r] = v.z;
            xT[(kq * 4 + 3) * 132 + r] = v.w;
        }
        // W tile 32x64
#pragma unroll
        for (int p = 0; p < 2; ++p) {
            int s = tid + p * 256;           // 0..511
            int kk = s >> 4, cq = s & 15;
            *(float4*)(ws + kk * 68 + cq * 4) =
                *(const float4*)(Win + (size_t)(k0 + kk) * DOUT + c0 + cq * 4);
        }
        __syncthreads();
#pragma unroll
        for (int kk = 0; kk < 32; ++kk) {
            float4 a0 = *(const float4*)(xT + kk * 132 + tr * 4);
            float4 a1 = *(const float4*)(xT + kk * 132 + 64 + tr * 4);
            float4 b4 = *(const float4*)(ws + kk * 68 + tc * 4);
            float av[8] = {a0.x, a0.y, a0.z, a0.w, a1.x, a1.y, a1.z, a1.w};
            float bv[4] = {b4.x, b4.y, b4.z, b4.w};
#pragma unroll
            for (int i = 0; i < 8; ++i)
#pragma unroll
                for (int j = 0; j < 4; ++j)
                    acc[i][j] = fmaf(av[i], bv[j], acc[i][j]);
        }
        __syncthreads();
    }

    float4 bb = *(const float4*)(bin + c0 + tc * 4);
#pragma unroll
    for (int i = 0; i < 8; ++i) {
        int r = (i < 4) ? (tr * 4 + i) : (64 + tr * 4 + (i - 4));
        float4 o;
        o.x = acc[i][0] + bb.x;
        o.y = acc[i][1] + bb.y;
        o.z = acc[i][2] + bb.z;
        o.w = acc[i][3] + bb.w;
        *(float4*)(out + (size_t)(n0 + r) * DOUT + c0 + tc * 4) = o;
    }
}

// ---------------------------------------------------------------------------
// Pass 2: one kernel per timestep (stream-ordered; kernel boundary gives
// device-wide visibility of h across XCDs, no fences needed).
// Grid 256 wgs = 4 row-groups(16 rows) x 64 col-groups(16 cols).
// Threads: cq = tid&3 (4 cols each), half = (tid>>2)&3 (K-chunk of 256),
//          r = tid>>4 (0..15). Cross-half reduce via shfl_xor(4), shfl_xor(8).
// h rows staged in LDS (exactly 64KB) with XOR swizzle so the 16-way
// row-broadcast reads are <=2-way bank conflicts.
// ---------------------------------------------------------------------------
__device__ __forceinline__ int hswz(int r, int idx) {
    // xor row (low 4 banks) and fold idx bits 8-9 into bits 4-5 (K-half spread)
    return idx ^ r ^ ((idx >> 4) & 48);
}

__global__ __launch_bounds__(256) void step_kernel(
    int t, const float* __restrict__ h_in, float* __restrict__ h_out,
    const float* __restrict__ Wh, const float* __restrict__ periods,
    const float* __restrict__ shifts, float* __restrict__ out)
{
    __shared__ float hs[16 * 1024];  // 64KB exactly

    const int cg = blockIdx.x & 63;   // 0..63
    const int rg = blockIdx.x >> 6;   // 0..3
    const int c0 = cg * 16;
    const int r0 = rg * 16;
    const int tid = threadIdx.x;

    // stage h rows r0..r0+15 (swizzled)
    {
        const int row = tid >> 4;     // 0..15
        const int sb  = tid & 15;
#pragma unroll
        for (int i = 0; i < 16; ++i) {
            int s = sb + i * 16;      // float4 slot 0..255
            float4 v = *(const float4*)(h_in + (size_t)(r0 + row) * DOUT + s * 4);
            int base = row * 1024;
            hs[base + hswz(row, s * 4 + 0)] = v.x;
            hs[base + hswz(row, s * 4 + 1)] = v.y;
            hs[base + hswz(row, s * 4 + 2)] = v.z;
            hs[base + hswz(row, s * 4 + 3)] = v.w;
        }
    }
    __syncthreads();

    const int cq   = tid & 3;          // 4 cols
    const int half = (tid >> 2) & 3;   // K chunk of 256
    const int r    = tid >> 4;         // 0..15
    const int c    = c0 + cq * 4;
    const int k0h  = half * 256;
    const float* wp = Wh + c;
    const float* hp = hs + r * 1024;

    float a0 = 0.f, a1 = 0.f, a2 = 0.f, a3 = 0.f;
#pragma unroll 16
    for (int k = 0; k < 256; ++k) {
        int kk = k0h + k;
        float4 w4 = *(const float4*)(wp + (size_t)kk * DOUT);
        float hv = hp[hswz(r, kk)];
        a0 = fmaf(hv, w4.x, a0);
        a1 = fmaf(hv, w4.y, a1);
        a2 = fmaf(hv, w4.z, a2);
        a3 = fmaf(hv, w4.w, a3);
    }
    // reduce across the 4 K-halves (lane bits 2-3)
    a0 += __shfl_xor(a0, 4); a0 += __shfl_xor(a0, 8);
    a1 += __shfl_xor(a1, 4); a1 += __shfl_xor(a1, 8);
    a2 += __shfl_xor(a2, 4); a2 += __shfl_xor(a2, 8);
    a3 += __shfl_xor(a3, 4); a3 += __shfl_xor(a3, 8);

    if (half == 0) {
        const int m = c >> 7;  // module index (4-col group never crosses a 128 boundary)
        const float g  = 0.5f * (sinf((float)t * periods[m] + shifts[m]) + 1.0f);
        const float og = 1.0f - g;

        const size_t zidx = (size_t)(r0 + r) * ((size_t)Tz * DOUT) + (size_t)t * DOUT + c;
        float4 z4 = *(const float4*)(out + zidx);
        float h0 = hp[hswz(r, c + 0)];
        float h1 = hp[hswz(r, c + 1)];
        float h2 = hp[hswz(r, c + 2)];
        float h3 = hp[hswz(r, c + 3)];
        float4 y;
        y.x = og * tanhf(z4.x + a0) + g * h0;
        y.y = og * tanhf(z4.y + a1) + g * h1;
        y.z = og * tanhf(z4.z + a2) + g * h2;
        y.w = og * tanhf(z4.w + a3) + g * h3;
        *(float4*)(out + zidx) = y;                                   // ys[b,t,:]
        *(float4*)(h_out + (size_t)(r0 + r) * DOUT + c) = y;          // next h
        if (t == Tz - 1)
            *(float4*)(out + (size_t)Bz * Tz * DOUT + (size_t)(r0 + r) * DOUT + c) = y;
    }
}

// ---------------------------------------------------------------------------
extern "C" void kernel_launch(void* const* d_in, const int* in_sizes, int n_in,
                              void* d_out, int out_size, void* d_ws, size_t ws_size,
                              hipStream_t stream)
{
    const float* x   = (const float*)d_in[0];
    const float* Win = (const float*)d_in[1];
    const float* bin = (const float*)d_in[2];
    const float* Wh  = (const float*)d_in[3];
    const float* per = (const float*)d_in[4];
    const float* shf = (const float*)d_in[5];
    float* out = (float*)d_out;

    float* ha = (float*)d_ws;                   // h ping
    float* hb = ha + (size_t)Bz * DOUT;         // h pong

    hipMemsetAsync(ha, 0, (size_t)Bz * DOUT * sizeof(float), stream);  // h0 = 0
    zgemm_kernel<<<dim3(256, 16), 256, 0, stream>>>(x, Win, bin, out);
    for (int t = 0; t < Tz; ++t) {
        step_kernel<<<256, 256, 0, stream>>>(t, ha, hb, Wh, per, shf, out);
        float* tmp = ha; ha = hb; hb = tmp;
    }
}